// Round 1
// baseline (1674.856 us; speedup 1.0000x reference)
//
#include <hip/hip_runtime.h>
#include <hip/hip_bf16.h>

#define NB 1024
#define NT 256
#define NC 512
#define NH 64

typedef __attribute__((ext_vector_type(8))) short bf16x8;   // 8 bf16 (4 VGPRs)
typedef __attribute__((ext_vector_type(4))) float f32x4;

__device__ __forceinline__ short f2bf(float f) {
    unsigned u = __builtin_bit_cast(unsigned, f);
    u = (u + 0x7FFFu + ((u >> 16) & 1u)) >> 16;   // RNE
    return (short)u;
}

// Kernel 0: swizzle Wq|Wk|Wv (fp32 [512,64]) into bf16 B-fragment layout.
// wsw[tg][c][quad][l16][j] = W_combined[c*32+quad*8+j][tg*16+l16], tg in [0,12)
__global__ void swzw(const float* __restrict__ Wq, const float* __restrict__ Wk,
                     const float* __restrict__ Wv, short* __restrict__ wsw) {
    int tid = blockIdx.x * 256 + threadIdx.x;    // 98304 total
    int j    = tid & 7;
    int l16  = (tid >> 3) & 15;
    int quad = (tid >> 7) & 3;
    int c    = (tid >> 9) & 15;
    int tg   = tid >> 13;                        // 0..11
    const float* W = (tg < 4) ? Wq : (tg < 8) ? Wk : Wv;
    int h = (tg & 3) * 16 + l16;
    int k = c * 32 + quad * 8 + j;
    wsw[tid] = f2bf(W[k * NH + h]);
}

// LDS layout (shorts): [0,16384) q (A-frag swizzle; reused as P scratch in phase B)
//                      [16384,32768) k (B-frag swizzle for QK^T)
//                      [32768,49152) v (B-frag swizzle for PV)
// qk swizzle:  idx(row,h) = (row>>4)*1024 + (h>>5)*512 + ((h>>3)&3)*128 + (row&15)*8 + (h&7)
// v  swizzle:  idx(s, h)  = (s>>5)*2048 + (h>>4)*512 + ((s>>3)&3)*128 + (h&15)*8 + (s&7)
__global__ __launch_bounds__(256, 1)
void attn_fused(const float* __restrict__ x, const short* __restrict__ wsw,
                float* __restrict__ out) {
    __shared__ short lds[49152];   // 96 KB
    const int b    = blockIdx.x;
    const int tid  = threadIdx.x;
    const int w    = tid >> 6;     // wave 0..3
    const int lane = tid & 63;
    const int l16  = lane & 15;
    const int quad = lane >> 4;

    const float* xb = x + (size_t)b * NT * NC;

    // ---------------- Phase A: fused QKV projection ----------------
    // wave w computes combined cols [48w, 48w+48) for all 256 rows.
    for (int g = 0; g < 4; ++g) {           // row groups of 64
        f32x4 acc[4][3];
        #pragma unroll
        for (int rr = 0; rr < 4; ++rr)
            #pragma unroll
            for (int tt = 0; tt < 3; ++tt)
                acc[rr][tt] = (f32x4){0.f, 0.f, 0.f, 0.f};

        for (int c = 0; c < 16; ++c) {      // K chunks of 32
            bf16x8 af[4];
            #pragma unroll
            for (int rr = 0; rr < 4; ++rr) {
                const float* p = xb + (size_t)((g * 4 + rr) * 16 + l16) * NC + c * 32 + quad * 8;
                f32x4 a0 = *(const f32x4*)p;
                f32x4 a1 = *(const f32x4*)(p + 4);
                bf16x8 fr;
                fr[0] = f2bf(a0[0]); fr[1] = f2bf(a0[1]); fr[2] = f2bf(a0[2]); fr[3] = f2bf(a0[3]);
                fr[4] = f2bf(a1[0]); fr[5] = f2bf(a1[1]); fr[6] = f2bf(a1[2]); fr[7] = f2bf(a1[3]);
                af[rr] = fr;
            }
            bf16x8 bfr[3];
            #pragma unroll
            for (int tt = 0; tt < 3; ++tt) {
                int tg = 3 * w + tt;
                bfr[tt] = *(const bf16x8*)(wsw + (size_t)((tg * 16 + c) * 64 + lane) * 8);
            }
            #pragma unroll
            for (int rr = 0; rr < 4; ++rr)
                #pragma unroll
                for (int tt = 0; tt < 3; ++tt)
                    acc[rr][tt] = __builtin_amdgcn_mfma_f32_16x16x32_bf16(af[rr], bfr[tt], acc[rr][tt], 0, 0, 0);
        }

        // scatter accumulators into swizzled LDS (mat is wave-uniform per tt)
        #pragma unroll
        for (int tt = 0; tt < 3; ++tt) {
            int gcol = w * 48 + tt * 16 + l16;   // 0..191
            int mat  = gcol >> 6;                // 0=q 1=k 2=v
            int h    = gcol & 63;
            #pragma unroll
            for (int rr = 0; rr < 4; ++rr) {
                #pragma unroll
                for (int r = 0; r < 4; ++r) {
                    int row = (g * 4 + rr) * 16 + quad * 4 + r;
                    float v = acc[rr][tt][r];
                    int idx;
                    if (mat == 0) {
                        v *= 0.125f;   // fold softmax scale into q (exact pow2)
                        idx = (row >> 4) * 1024 + (h >> 5) * 512 + ((h >> 3) & 3) * 128 + (row & 15) * 8 + (h & 7);
                    } else if (mat == 1) {
                        idx = 16384 + (row >> 4) * 1024 + (h >> 5) * 512 + ((h >> 3) & 3) * 128 + (row & 15) * 8 + (h & 7);
                    } else {
                        idx = 32768 + (row >> 5) * 2048 + (h >> 4) * 512 + ((row >> 3) & 3) * 128 + (h & 15) * 8 + (row & 7);
                    }
                    lds[idx] = f2bf(v);
                }
            }
        }
    }
    __syncthreads();

    // ---------------- Phase B: causal attention ----------------
    const int rts[4] = { w, 7 - w, 8 + w, 15 - w };   // balanced causal work
    bf16x8 qf[4][2];
    #pragma unroll
    for (int i = 0; i < 4; ++i)
        #pragma unroll
        for (int c = 0; c < 2; ++c)
            qf[i][c] = *(const bf16x8*)(lds + rts[i] * 1024 + c * 512 + quad * 128 + l16 * 8);
    __syncthreads();   // everyone has q; q region becomes per-wave P scratch

    short*       pb = lds + w * 4096;   // 16 rows x 256 s, A-frag layout
    const short* kb = lds + 16384;
    const short* vb = lds + 32768;

    for (int i = 0; i < 4; ++i) {
        const int R = rts[i];           // query row-tile (wave-uniform)
        f32x4 sacc[16];
        #pragma unroll
        for (int ct = 0; ct < 16; ++ct) sacc[ct] = (f32x4){0.f, 0.f, 0.f, 0.f};

        // S = q k^T (scale pre-folded), causal mask on diagonal tile
        #pragma unroll
        for (int ct = 0; ct < 16; ++ct) {
            if (ct <= R) {
                #pragma unroll
                for (int c = 0; c < 2; ++c) {
                    bf16x8 kf = *(const bf16x8*)(kb + ct * 1024 + c * 512 + quad * 128 + l16 * 8);
                    sacc[ct] = __builtin_amdgcn_mfma_f32_16x16x32_bf16(qf[i][c], kf, sacc[ct], 0, 0, 0);
                }
                if (ct == R) {
                    #pragma unroll
                    for (int r = 0; r < 4; ++r)
                        if (l16 > quad * 4 + r) sacc[ct][r] = -1e30f;
                }
            }
        }

        // softmax: row = quad*4+r lives across the 16 lanes of this quad-group
        float m0[4], lsum[4];
        #pragma unroll
        for (int r = 0; r < 4; ++r) m0[r] = -1e30f;
        #pragma unroll
        for (int ct = 0; ct < 16; ++ct)
            if (ct <= R)
                #pragma unroll
                for (int r = 0; r < 4; ++r) m0[r] = fmaxf(m0[r], sacc[ct][r]);
        #pragma unroll
        for (int mk = 1; mk <= 8; mk <<= 1)
            #pragma unroll
            for (int r = 0; r < 4; ++r) m0[r] = fmaxf(m0[r], __shfl_xor(m0[r], mk));
        #pragma unroll
        for (int r = 0; r < 4; ++r) lsum[r] = 0.f;
        #pragma unroll
        for (int ct = 0; ct < 16; ++ct)
            if (ct <= R)
                #pragma unroll
                for (int r = 0; r < 4; ++r) {
                    float pv = __expf(sacc[ct][r] - m0[r]);
                    sacc[ct][r] = pv;
                    lsum[r] += pv;
                }
        #pragma unroll
        for (int mk = 1; mk <= 8; mk <<= 1)
            #pragma unroll
            for (int r = 0; r < 4; ++r) lsum[r] += __shfl_xor(lsum[r], mk);

        // scatter P into A-frag layout (zero tile R+1 when it shares a k-chunk)
        #pragma unroll
        for (int ct = 0; ct < 16; ++ct) {
            int s    = ct * 16 + l16;
            int base = (s >> 5) * 512 + ((s >> 3) & 3) * 128 + (s & 7);
            if (ct <= R) {
                #pragma unroll
                for (int r = 0; r < 4; ++r)
                    pb[base + (quad * 4 + r) * 8] = f2bf(sacc[ct][r]);
            } else if (ct == R + 1 && ((R & 1) == 0)) {
                #pragma unroll
                for (int r = 0; r < 4; ++r)
                    pb[base + (quad * 4 + r) * 8] = 0;
            }
        }

        // O = P V
        f32x4 oacc[4];
        #pragma unroll
        for (int t = 0; t < 4; ++t) oacc[t] = (f32x4){0.f, 0.f, 0.f, 0.f};
        const int cmax = (R + 2) >> 1;
        #pragma unroll
        for (int c2 = 0; c2 < 8; ++c2) {
            if (c2 < cmax) {
                bf16x8 pf = *(const bf16x8*)(pb + c2 * 512 + quad * 128 + l16 * 8);
                #pragma unroll
                for (int t = 0; t < 4; ++t) {
                    bf16x8 vf = *(const bf16x8*)(vb + c2 * 2048 + t * 512 + quad * 128 + l16 * 8);
                    oacc[t] = __builtin_amdgcn_mfma_f32_16x16x32_bf16(pf, vf, oacc[t], 0, 0, 0);
                }
            }
        }

        float inv[4];
        #pragma unroll
        for (int r = 0; r < 4; ++r) inv[r] = 1.0f / lsum[r];
        float* ob = out + ((size_t)b * NT + R * 16 + quad * 4) * NH + l16;
        #pragma unroll
        for (int t = 0; t < 4; ++t)
            #pragma unroll
            for (int r = 0; r < 4; ++r)
                ob[(size_t)r * NH + t * 16] = oacc[t][r] * inv[r];
    }
}

extern "C" void kernel_launch(void* const* d_in, const int* in_sizes, int n_in,
                              void* d_out, int out_size, void* d_ws, size_t ws_size,
                              hipStream_t stream) {
    const float* x  = (const float*)d_in[0];
    const float* Wq = (const float*)d_in[1];
    const float* Wk = (const float*)d_in[2];
    const float* Wv = (const float*)d_in[3];
    float* outp = (float*)d_out;
    short* wsw  = (short*)d_ws;    // needs 98304 shorts = 192 KB

    swzw<<<384, 256, 0, stream>>>(Wq, Wk, Wv, wsw);
    attn_fused<<<NB, 256, 0, stream>>>(x, wsw, outp);
}

// Round 2
// 1117.272 us; speedup vs baseline: 1.4991x; 1.4991x over previous
//
#include <hip/hip_runtime.h>
#include <hip/hip_bf16.h>

#define NB 1024
#define NT 256
#define NC 512
#define NH 64

typedef __attribute__((ext_vector_type(8))) short bf16x8;   // 8 bf16 (4 VGPRs)
typedef __attribute__((ext_vector_type(4))) float f32x4;
typedef __attribute__((ext_vector_type(4))) short s16x4;
typedef __attribute__((ext_vector_type(4))) int   i32x4;

__device__ __forceinline__ short f2bf(float f) {
    unsigned u = __builtin_bit_cast(unsigned, f);
    u = (u + 0x7FFFu + ((u >> 16) & 1u)) >> 16;   // RNE
    return (short)u;
}

__device__ __forceinline__ bf16x8 cvt8(f32x4 a0, f32x4 a1) {
#if defined(__has_builtin) && __has_builtin(__builtin_amdgcn_cvt_pk_bf16_f32)
    i32x4 pk;
    pk[0] = __builtin_bit_cast(int, __builtin_amdgcn_cvt_pk_bf16_f32(a0[0], a0[1]));
    pk[1] = __builtin_bit_cast(int, __builtin_amdgcn_cvt_pk_bf16_f32(a0[2], a0[3]));
    pk[2] = __builtin_bit_cast(int, __builtin_amdgcn_cvt_pk_bf16_f32(a1[0], a1[1]));
    pk[3] = __builtin_bit_cast(int, __builtin_amdgcn_cvt_pk_bf16_f32(a1[2], a1[3]));
    return __builtin_bit_cast(bf16x8, pk);
#else
    bf16x8 r;
    r[0] = f2bf(a0[0]); r[1] = f2bf(a0[1]); r[2] = f2bf(a0[2]); r[3] = f2bf(a0[3]);
    r[4] = f2bf(a1[0]); r[5] = f2bf(a1[1]); r[6] = f2bf(a1[2]); r[7] = f2bf(a1[3]);
    return r;
#endif
}

// Kernel 0: swizzle Wq|Wk|Wv (fp32 [512,64]) into bf16 B-fragment layout.
// wsw[tg][c][quad][l16][j] = W_combined[c*32+quad*8+j][tg*16+l16], tg in [0,12)
__global__ void swzw(const float* __restrict__ Wq, const float* __restrict__ Wk,
                     const float* __restrict__ Wv, short* __restrict__ wsw) {
    int tid = blockIdx.x * 256 + threadIdx.x;    // 98304 total
    int j    = tid & 7;
    int l16  = (tid >> 3) & 15;
    int quad = (tid >> 7) & 3;
    int c    = (tid >> 9) & 15;
    int tg   = tid >> 13;                        // 0..11
    const float* W = (tg < 4) ? Wq : (tg < 8) ? Wk : Wv;
    int h = (tg & 3) * 16 + l16;
    int k = c * 32 + quad * 8 + j;
    wsw[tid] = f2bf(W[k * NH + h]);
}

// LDS (shorts): [0,16384) q B-frag swizzle (reused as per-wave P^T chunk scratch)
//               [16384,32768) k A/B-frag swizzle
//               [32768,49152) v frag swizzle
// qk swizzle:  idx(row,h) = (row>>4)*1024 + (h>>5)*512 + ((h>>3)&3)*128 + (row&15)*8 + (h&7)
// v  swizzle:  idx(s, h)  = (s>>5)*2048 + (h>>4)*512 + ((s>>3)&3)*128 + (h&15)*8 + (s&7)
__global__ __launch_bounds__(512, 2)
void attn_fused(const float* __restrict__ x, const short* __restrict__ wsw,
                float* __restrict__ out) {
    __shared__ short lds[49152];   // 96 KB
    const int b    = blockIdx.x;
    const int tid  = threadIdx.x;
    const int w    = tid >> 6;     // wave 0..7
    const int lane = tid & 63;
    const int l16  = lane & 15;
    const int quad = lane >> 4;

    const float* xb = x + (size_t)b * NT * NC;

    // ---------------- Phase A: fused QKV projection ----------------
    // wave (h2,c4): rows [128*h2,128*h2+128), combined cols [48*c4, 48*c4+48)
    const int h2 = w >> 2;
    const int c4 = w & 3;
    for (int g = 0; g < 2; ++g) {
        const int rbase = h2 * 128 + g * 64;
        f32x4 acc[4][3];
        #pragma unroll
        for (int rr = 0; rr < 4; ++rr)
            #pragma unroll
            for (int tt = 0; tt < 3; ++tt)
                acc[rr][tt] = (f32x4){0.f, 0.f, 0.f, 0.f};

        f32x4  ab[2][4][2];   // double-buffered x rows
        bf16x8 bb[2][3];      // double-buffered weight frags

        #pragma unroll
        for (int rr = 0; rr < 4; ++rr) {
            const float* p = xb + (size_t)(rbase + rr * 16 + l16) * NC + quad * 8;
            ab[0][rr][0] = *(const f32x4*)p;
            ab[0][rr][1] = *(const f32x4*)(p + 4);
        }
        #pragma unroll
        for (int tt = 0; tt < 3; ++tt)
            bb[0][tt] = *(const bf16x8*)(wsw + (size_t)(((c4 * 3 + tt) * 16) * 64 + lane) * 8);

        #pragma unroll
        for (int c = 0; c < 16; ++c) {
            const int cur = c & 1, nxt = cur ^ 1;
            if (c < 15) {   // software pipeline: issue next chunk's loads first
                #pragma unroll
                for (int rr = 0; rr < 4; ++rr) {
                    const float* p = xb + (size_t)(rbase + rr * 16 + l16) * NC + (c + 1) * 32 + quad * 8;
                    ab[nxt][rr][0] = *(const f32x4*)p;
                    ab[nxt][rr][1] = *(const f32x4*)(p + 4);
                }
                #pragma unroll
                for (int tt = 0; tt < 3; ++tt)
                    bb[nxt][tt] = *(const bf16x8*)(wsw + (size_t)(((c4 * 3 + tt) * 16 + c + 1) * 64 + lane) * 8);
            }
            bf16x8 af[4];
            #pragma unroll
            for (int rr = 0; rr < 4; ++rr) af[rr] = cvt8(ab[cur][rr][0], ab[cur][rr][1]);
            #pragma unroll
            for (int rr = 0; rr < 4; ++rr)
                #pragma unroll
                for (int tt = 0; tt < 3; ++tt)
                    acc[rr][tt] = __builtin_amdgcn_mfma_f32_16x16x32_bf16(af[rr], bb[cur][tt], acc[rr][tt], 0, 0, 0);
        }

        // scatter accumulators into swizzled LDS
        #pragma unroll
        for (int tt = 0; tt < 3; ++tt) {
            int gcol = c4 * 48 + tt * 16 + l16;   // 0..191
            int mat  = gcol >> 6;                 // 0=q 1=k 2=v (wave-uniform per tt)
            int h    = gcol & 63;
            #pragma unroll
            for (int rr = 0; rr < 4; ++rr) {
                #pragma unroll
                for (int r = 0; r < 4; ++r) {
                    int row = rbase + rr * 16 + quad * 4 + r;
                    float v = acc[rr][tt][r];
                    int idx;
                    if (mat == 0) {
                        v *= 0.125f;   // fold softmax scale into q
                        idx = (row >> 4) * 1024 + (h >> 5) * 512 + ((h >> 3) & 3) * 128 + (row & 15) * 8 + (h & 7);
                    } else if (mat == 1) {
                        idx = 16384 + (row >> 4) * 1024 + (h >> 5) * 512 + ((h >> 3) & 3) * 128 + (row & 15) * 8 + (h & 7);
                    } else {
                        idx = 32768 + (row >> 5) * 2048 + (h >> 4) * 512 + ((row >> 3) & 3) * 128 + (h & 15) * 8 + (row & 7);
                    }
                    lds[idx] = f2bf(v);
                }
            }
        }
    }
    __syncthreads();

    // ---------------- Phase B: causal attention, S^T formulation ----------------
    // S^T = K·Q^T via mfma(A=kf, B=qf) — identical fragment layouts, swapped roles.
    // D[m=s_local][n=t_local]: lane l16 = t, regs span s. Softmax over s is
    // in-lane + 2 cross-quad shuffles.
    const int rts[2] = { w, 15 - w };   // balanced: (w+1)+(16-w) = 17 tile-units
    bf16x8 qf[2][2];
    #pragma unroll
    for (int i = 0; i < 2; ++i)
        #pragma unroll
        for (int c = 0; c < 2; ++c)
            qf[i][c] = *(const bf16x8*)(lds + rts[i] * 1024 + c * 512 + quad * 128 + l16 * 8);
    __syncthreads();   // q region becomes per-wave P^T scratch

    short*       pb = lds + w * 512;    // 16 t x 32 s bf16 = 1 KB per wave
    const short* kb = lds + 16384;
    const short* vb = lds + 32768;

    #pragma unroll
    for (int i = 0; i < 2; ++i) {
        const int R = rts[i];           // query row-tile (wave-uniform)
        f32x4 sacc[16];
        #pragma unroll
        for (int ct = 0; ct < 16; ++ct) sacc[ct] = (f32x4){0.f, 0.f, 0.f, 0.f};

        #pragma unroll
        for (int ct = 0; ct < 16; ++ct) {
            if (ct <= R) {
                #pragma unroll
                for (int c = 0; c < 2; ++c) {
                    bf16x8 kf = *(const bf16x8*)(kb + ct * 1024 + c * 512 + quad * 128 + l16 * 8);
                    sacc[ct] = __builtin_amdgcn_mfma_f32_16x16x32_bf16(kf, qf[i][c], sacc[ct], 0, 0, 0);
                }
                if (ct == R) {   // causal: mask s_local > t_local
                    #pragma unroll
                    for (int r = 0; r < 4; ++r)
                        if (quad * 4 + r > l16) sacc[ct][r] = -1e30f;
                }
            }
        }

        // softmax over s: in-lane across regs/tiles, then cross-quad
        float m0 = -1e30f;
        #pragma unroll
        for (int ct = 0; ct < 16; ++ct)
            if (ct <= R)
                #pragma unroll
                for (int r = 0; r < 4; ++r) m0 = fmaxf(m0, sacc[ct][r]);
        m0 = fmaxf(m0, __shfl_xor(m0, 16));
        m0 = fmaxf(m0, __shfl_xor(m0, 32));
        float ls = 0.f;
        #pragma unroll
        for (int ct = 0; ct < 16; ++ct)
            if (ct <= R)
                #pragma unroll
                for (int r = 0; r < 4; ++r) {
                    float p = __expf(sacc[ct][r] - m0);
                    sacc[ct][r] = p;
                    ls += p;
                }
        ls += __shfl_xor(ls, 16);
        ls += __shfl_xor(ls, 32);

        // O^T = V^T · P^T, chunked P^T through 1 KB LDS scratch
        f32x4 oacc[4];
        #pragma unroll
        for (int ot = 0; ot < 4; ++ot) oacc[ot] = (f32x4){0.f, 0.f, 0.f, 0.f};

        #pragma unroll
        for (int c2 = 0; c2 < 8; ++c2) {
            if (c2 <= (R >> 1)) {
                #pragma unroll
                for (int half = 0; half < 2; ++half) {
                    int ct = 2 * c2 + half;
                    s16x4 vals;
                    if (ct <= R) {
                        #pragma unroll
                        for (int r = 0; r < 4; ++r) vals[r] = f2bf(sacc[ct][r]);
                    } else {
                        vals = (s16x4){0, 0, 0, 0};
                    }
                    // P^T[s=32c2+16*half+quad*4+r][t=l16], t-major rows of 32
                    *(s16x4*)(pb + l16 * 32 + half * 16 + quad * 4) = vals;
                }
                bf16x8 pf = *(const bf16x8*)(pb + l16 * 32 + quad * 8);
                #pragma unroll
                for (int ot = 0; ot < 4; ++ot) {
                    bf16x8 vf = *(const bf16x8*)(vb + c2 * 2048 + ot * 512 + quad * 128 + l16 * 8);
                    oacc[ot] = __builtin_amdgcn_mfma_f32_16x16x32_bf16(vf, pf, oacc[ot], 0, 0, 0);
                }
            }
        }

        // O^T C-layout: lane l16 = t_local (so ls/inv is lane-uniform across regs),
        // regs = h = ot*16 + quad*4 + r
        float inv = 1.0f / ls;
        float* ob = out + ((size_t)b * NT + R * 16 + l16) * NH;
        #pragma unroll
        for (int ot = 0; ot < 4; ++ot) {
            f32x4 o;
            #pragma unroll
            for (int r = 0; r < 4; ++r) o[r] = oacc[ot][r] * inv;
            *(f32x4*)(ob + ot * 16 + quad * 4) = o;
        }
    }
}

extern "C" void kernel_launch(void* const* d_in, const int* in_sizes, int n_in,
                              void* d_out, int out_size, void* d_ws, size_t ws_size,
                              hipStream_t stream) {
    const float* x  = (const float*)d_in[0];
    const float* Wq = (const float*)d_in[1];
    const float* Wk = (const float*)d_in[2];
    const float* Wv = (const float*)d_in[3];
    float* outp = (float*)d_out;
    short* wsw  = (short*)d_ws;    // 98304 shorts = 192 KB

    swzw<<<384, 256, 0, stream>>>(Wq, Wk, Wv, wsw);
    attn_fused<<<NB, 512, 0, stream>>>(x, wsw, outp);
}